// Round 1
// baseline (501.699 us; speedup 1.0000x reference)
//
#include <hip/hip_runtime.h>
#include <math.h>

#define NN 87      // N == K == 87
#define ES 92      // sE / sA row stride (floats); 92 mod 32 = 28 -> <=2-way conflicts on float4
#define XS 180     // sXD / sW row stride (floats); 180 mod 32 = 20 -> <=2-way conflicts on float4
#define NT 256

// LDS plan (floats):
//   uni[96*ES*2] = 17664   : phase A = sE(96x92) + sA(96x92) ; phase B = sW(96x180=17280)
//   sXD[96*XS]   = 17280   : [ x (cols 0..86) | 0 (col 87) | D (cols 88..174) | 0 (col 175) ]
// total ~140.5 KB -> 1 block/CU, 4 waves.

__global__ __launch_bounds__(NT, 1)
void fused_diffusion_mlp(const float* __restrict__ x,
                         const float* __restrict__ evals,
                         const float* __restrict__ evecs,
                         const float* __restrict__ dtime,
                         const float* __restrict__ W,
                         const float* __restrict__ bias,
                         float* __restrict__ out)
{
    __shared__ float uni[96 * ES * 2];
    __shared__ float sXD[96 * XS];
    __shared__ float sEval[NN];
    __shared__ float sT[NN];

    float* const sE = uni;
    float* const sA = uni + 96 * ES;
    float* const sW = uni;

    const int b   = (int)blockIdx.x;
    const int tid = (int)threadIdx.x;
    const int tx  = tid & 15;
    const int ty  = tid >> 4;

    const float* __restrict__ Eb = evecs + (size_t)b * (NN * NN);
    const float* __restrict__ xb = x     + (size_t)b * (NN * NN);

    // ---------------- P1: stage evecs + x, evals + clamped t, zero all pads ----------------
    for (int idx = tid; idx < NN * NN; idx += NT) {
        const int i = idx / NN;
        const int m = idx - i * NN;
        sE[i * ES + m]  = Eb[idx];
        sXD[i * XS + m] = xb[idx];
    }
    if (tid < NN) {
        sEval[tid] = evals[(size_t)b * NN + tid];
        sT[tid]    = fmaxf(dtime[tid], 1e-8f);
    }
    // sE/sA pad cols 87..91 (all 96 rows)
    for (int idx = tid; idx < 96 * 5; idx += NT) {
        const int r = idx / 5, c = NN + (idx % 5);
        sE[r * ES + c] = 0.f;
        sA[r * ES + c] = 0.f;
    }
    // sE/sA pad rows 87..95 (cols 0..86)
    for (int idx = tid; idx < 9 * NN; idx += NT) {
        const int r = NN + idx / NN, c = idx % NN;
        sE[r * ES + c] = 0.f;
        sA[r * ES + c] = 0.f;
    }
    // sXD: seam col 87 (all rows), and x-half pad rows 87..95 (cols 0..87)
    for (int r = tid; r < 96; r += NT) sXD[r * XS + NN] = 0.f;
    for (int idx = tid; idx < 9 * 88; idx += NT) {
        const int r = NN + idx / 88, c = idx % 88;
        sXD[r * XS + c] = 0.f;
    }
    __syncthreads();

    // ---------------- P2: A[i,m] = E[i,m] * exp(-t_i * eval_m) ----------------
    for (int idx = tid; idx < NN * NN; idx += NT) {
        const int i = idx / NN;
        const int m = idx - i * NN;
        sA[i * ES + m] = sE[i * ES + m] * __expf(-sT[i] * sEval[m]);
    }
    __syncthreads();

    // ---------------- P3: D = A @ E^T  -> sXD cols 88..175 ----------------
    {
        float acc[6][6];
        #pragma unroll
        for (int a = 0; a < 6; ++a)
            #pragma unroll
            for (int c = 0; c < 6; ++c) acc[a][c] = 0.f;

        for (int m = 0; m < 88; m += 4) {
            float4 af[6], bf[6];
            #pragma unroll
            for (int a = 0; a < 6; ++a)
                af[a] = *reinterpret_cast<const float4*>(&sA[(ty + 16 * a) * ES + m]);
            #pragma unroll
            for (int c = 0; c < 6; ++c)
                bf[c] = *reinterpret_cast<const float4*>(&sE[(tx + 16 * c) * ES + m]);
            #pragma unroll
            for (int a = 0; a < 6; ++a)
                #pragma unroll
                for (int c = 0; c < 6; ++c) {
                    acc[a][c] += af[a].x * bf[c].x;
                    acc[a][c] += af[a].y * bf[c].y;
                    acc[a][c] += af[a].z * bf[c].z;
                    acc[a][c] += af[a].w * bf[c].w;
                }
        }

        // store D tile; j<=87 keeps col <= 175 in range (acc rows/cols >=88 are 0 anyway)
        #pragma unroll
        for (int a = 0; a < 6; ++a) {
            const int i = ty + 16 * a;
            #pragma unroll
            for (int c = 0; c < 6; ++c) {
                const int j = tx + 16 * c;
                if (j <= NN) sXD[i * XS + 88 + j] = acc[a][c];
            }
        }
    }
    __syncthreads();   // all reads of sE/sA done -> union can be reused for W

    // ---------------- P4: load W into union: W1 -> cols 0..86, W2 -> cols 88..174 ----------------
    for (int idx = tid; idx < NN * 2 * NN; idx += NT) {
        const int j = idx / (2 * NN);
        const int k = idx - j * (2 * NN);
        const int c = (k < NN) ? k : (k + 1);
        sW[j * XS + c] = W[idx];
    }
    for (int r = tid; r < 96; r += NT) {
        sW[r * XS + NN]  = 0.f;   // seam col 87
        sW[r * XS + 175] = 0.f;   // seam col 175
    }
    for (int idx = tid; idx < 9 * 176; idx += NT) {   // pad rows 87..95
        const int r = NN + idx / 176, c = idx % 176;
        sW[r * XS + c] = 0.f;
    }
    __syncthreads();

    // ---------------- P5: out = [x|D] @ W^T + bias ----------------
    {
        float acc[6][6];
        #pragma unroll
        for (int a = 0; a < 6; ++a)
            #pragma unroll
            for (int c = 0; c < 6; ++c) acc[a][c] = 0.f;

        for (int k = 0; k < 176; k += 4) {
            float4 xa[6], wb[6];
            #pragma unroll
            for (int a = 0; a < 6; ++a)
                xa[a] = *reinterpret_cast<const float4*>(&sXD[(ty + 16 * a) * XS + k]);
            #pragma unroll
            for (int c = 0; c < 6; ++c)
                wb[c] = *reinterpret_cast<const float4*>(&sW[(tx + 16 * c) * XS + k]);
            #pragma unroll
            for (int a = 0; a < 6; ++a)
                #pragma unroll
                for (int c = 0; c < 6; ++c) {
                    acc[a][c] += xa[a].x * wb[c].x;
                    acc[a][c] += xa[a].y * wb[c].y;
                    acc[a][c] += xa[a].z * wb[c].z;
                    acc[a][c] += xa[a].w * wb[c].w;
                }
        }

        float bj[6];
        #pragma unroll
        for (int c = 0; c < 6; ++c) {
            const int j = tx + 16 * c;
            bj[c] = (j < NN) ? bias[j] : 0.f;
        }

        float* __restrict__ ob = out + (size_t)b * (NN * NN);
        #pragma unroll
        for (int a = 0; a < 6; ++a) {
            const int i = ty + 16 * a;
            if (i < NN) {
                #pragma unroll
                for (int c = 0; c < 6; ++c) {
                    const int j = tx + 16 * c;
                    if (j < NN) ob[i * NN + j] = acc[a][c] + bj[c];
                }
            }
        }
    }
}

extern "C" void kernel_launch(void* const* d_in, const int* in_sizes, int n_in,
                              void* d_out, int out_size, void* d_ws, size_t ws_size,
                              hipStream_t stream)
{
    const float* x     = (const float*)d_in[0];
    const float* evals = (const float*)d_in[1];
    const float* evecs = (const float*)d_in[2];
    const float* dtime = (const float*)d_in[3];
    const float* W     = (const float*)d_in[4];
    const float* bias  = (const float*)d_in[5];
    float* out = (float*)d_out;

    const int B = in_sizes[1] / NN;   // evals is (B, 87)

    fused_diffusion_mlp<<<dim3(B), dim3(NT), 0, stream>>>(x, evals, evecs, dtime, W, bias, out);
}

// Round 2
// 174.885 us; speedup vs baseline: 2.8687x; 2.8687x over previous
//
#include <hip/hip_runtime.h>
#include <math.h>

#define NN 87
#define RP 96            // padded rows/cols
#define SP 104           // panel row stride in bf16 elems; 208B = 13*16B -> conflict-friendly
#define NT 256
#define PANEL (RP * SP)  // 9984 elems

typedef __attribute__((ext_vector_type(8))) short bf16x8;
typedef __attribute__((ext_vector_type(4))) float f32x4;

__device__ __forceinline__ short f2bf(float f) {
    union { float f; unsigned u; } v; v.f = f;
    unsigned r = v.u + 0x7FFFu + ((v.u >> 16) & 1u);   // RNE
    return (short)(r >> 16);
}
__device__ __forceinline__ float bf2f(short s) {
    union { unsigned u; float f; } v;
    v.u = ((unsigned)(unsigned short)s) << 16;
    return v.f;
}

// Convert W (87 x 174 fp32) into two zero-padded bf16 panels in ws:
//   panel0[r][c] = W[r][c]       (x half)     r<87,c<87
//   panel1[r][c] = W[r][87+c]    (kernel half)
__global__ void prep_w(const float* __restrict__ W, short* __restrict__ wsb) {
    int idx = blockIdx.x * NT + threadIdx.x;
    if (idx >= 2 * PANEL) return;
    int p = idx / PANEL, rem = idx - p * PANEL;
    int r = rem / SP, c = rem - r * SP;
    short v = 0;
    if (r < NN && c < NN) v = f2bf(W[r * (2 * NN) + p * NN + c]);
    wsb[idx] = v;
}

template <bool WLDS>
__global__ __launch_bounds__(NT, 2)
void fused(const float* __restrict__ x, const float* __restrict__ evals,
           const float* __restrict__ evecs, const float* __restrict__ dtime,
           const float* __restrict__ W, const float* __restrict__ bias,
           const short* __restrict__ wsb, float* __restrict__ out)
{
    __shared__ __align__(16) short sE[PANEL];
    __shared__ __align__(16) short sA[PANEL];
    __shared__ __align__(16) short sX[PANEL];
    __shared__ __align__(16) short sD[PANEL];
    __shared__ float sEval[RP];
    __shared__ float sT[RP];
    __shared__ __align__(16) short sW[WLDS ? 2 * PANEL : 2];

    const int b   = (int)blockIdx.x;
    const int tid = (int)threadIdx.x;

    const float* __restrict__ Eb = evecs + (size_t)b * (NN * NN);
    const float* __restrict__ xb = x     + (size_t)b * (NN * NN);

    // ---------------- P1: stage evecs + x as bf16, zero pads ----------------
    for (int idx = tid; idx < NN * NN; idx += NT) {
        int i = idx / NN, m = idx - i * NN;
        sE[i * SP + m] = f2bf(Eb[idx]);
        sX[i * SP + m] = f2bf(xb[idx]);
    }
    if (tid < RP) {
        sEval[tid] = (tid < NN) ? evals[(size_t)b * NN + tid] : 0.f;
        sT[tid]    = (tid < NN) ? fmaxf(dtime[tid], 1e-8f) : 0.f;
    }
    // pad cols NN..95 (all 96 rows)
    for (int idx = tid; idx < RP * (RP - NN); idx += NT) {
        int r = idx / (RP - NN), c = NN + idx % (RP - NN);
        sE[r * SP + c] = 0; sA[r * SP + c] = 0; sX[r * SP + c] = 0;
    }
    // pad rows NN..95 (cols 0..86)
    for (int idx = tid; idx < (RP - NN) * NN; idx += NT) {
        int r = NN + idx / NN, c = idx % NN;
        sE[r * SP + c] = 0; sA[r * SP + c] = 0; sX[r * SP + c] = 0;
    }
    if constexpr (WLDS) {
        for (int idx = tid; idx < 2 * PANEL; idx += NT) {
            int p = idx / PANEL, rem = idx - p * PANEL;
            int r = rem / SP, c = rem - r * SP;
            sW[idx] = (r < NN && c < NN) ? f2bf(W[r * (2 * NN) + p * NN + c]) : (short)0;
        }
    }
    __syncthreads();

    // ---------------- P2: A = E * exp(-t_i * eval_m) ----------------
    for (int idx = tid; idx < NN * NN; idx += NT) {
        int i = idx / NN, m = idx - i * NN;
        float e = bf2f(sE[i * SP + m]);
        sA[i * SP + m] = f2bf(e * __expf(-sT[i] * sEval[m]));
    }
    __syncthreads();

    // ---------------- wave -> tile mapping ----------------
    const int lane = tid & 63;
    const int wave = tid >> 6;
    const int l15  = lane & 15;
    const int lk   = lane >> 4;          // 0..3
    const int i0   = (wave >> 1) * 48;   // 0 or 48
    const int j0   = (wave & 1) * 48;

    // ---------------- P3: GEMM1  D = A @ E^T  (MFMA) ----------------
    {
        f32x4 acc[3][3];
        #pragma unroll
        for (int r = 0; r < 3; ++r)
            #pragma unroll
            for (int c = 0; c < 3; ++c)
                acc[r][c] = (f32x4){0.f, 0.f, 0.f, 0.f};

        #pragma unroll
        for (int ks = 0; ks < 3; ++ks) {
            const int k0 = ks * 32 + lk * 8;
            bf16x8 af[3], ef[3];
            #pragma unroll
            for (int r = 0; r < 3; ++r)
                af[r] = *(const bf16x8*)&sA[(i0 + 16 * r + l15) * SP + k0];
            #pragma unroll
            for (int c = 0; c < 3; ++c)
                ef[c] = *(const bf16x8*)&sE[(j0 + 16 * c + l15) * SP + k0];
            #pragma unroll
            for (int r = 0; r < 3; ++r)
                #pragma unroll
                for (int c = 0; c < 3; ++c)
                    acc[r][c] = __builtin_amdgcn_mfma_f32_16x16x32_bf16(
                        af[r], ef[c], acc[r][c], 0, 0, 0);
        }

        // store D (bf16) into sD; pad rows/cols naturally receive zeros
        #pragma unroll
        for (int r = 0; r < 3; ++r) {
            const int ib = i0 + 16 * r + lk * 4;
            #pragma unroll
            for (int c = 0; c < 3; ++c) {
                const int j = j0 + 16 * c + l15;
                #pragma unroll
                for (int q = 0; q < 4; ++q)
                    sD[(ib + q) * SP + j] = f2bf(acc[r][c][q]);
            }
        }
    }
    __syncthreads();

    // ---------------- P5: GEMM2  out = [x|D] @ W^T + bias ----------------
    {
        f32x4 acc[3][3];
        #pragma unroll
        for (int r = 0; r < 3; ++r)
            #pragma unroll
            for (int c = 0; c < 3; ++c)
                acc[r][c] = (f32x4){0.f, 0.f, 0.f, 0.f};

        #pragma unroll
        for (int ks = 0; ks < 6; ++ks) {
            const short* Ab = (ks < 3) ? sX : sD;
            const short* Wb;
            if constexpr (WLDS) Wb = sW + ((ks < 3) ? 0 : PANEL);
            else                Wb = wsb + ((ks < 3) ? 0 : PANEL);
            const int k0 = ((ks < 3) ? ks : ks - 3) * 32 + lk * 8;

            bf16x8 af[3], wf[3];
            #pragma unroll
            for (int r = 0; r < 3; ++r)
                af[r] = *(const bf16x8*)&Ab[(i0 + 16 * r + l15) * SP + k0];
            #pragma unroll
            for (int c = 0; c < 3; ++c)
                wf[c] = *(const bf16x8*)&Wb[(j0 + 16 * c + l15) * SP + k0];
            #pragma unroll
            for (int r = 0; r < 3; ++r)
                #pragma unroll
                for (int c = 0; c < 3; ++c)
                    acc[r][c] = __builtin_amdgcn_mfma_f32_16x16x32_bf16(
                        af[r], wf[c], acc[r][c], 0, 0, 0);
        }

        float* __restrict__ ob = out + (size_t)b * (NN * NN);
        #pragma unroll
        for (int c = 0; c < 3; ++c) {
            const int j = j0 + 16 * c + l15;
            if (j < NN) {
                const float bj = bias[j];
                #pragma unroll
                for (int r = 0; r < 3; ++r) {
                    const int ib = i0 + 16 * r + lk * 4;
                    #pragma unroll
                    for (int q = 0; q < 4; ++q) {
                        const int i = ib + q;
                        if (i < NN) ob[i * NN + j] = acc[r][c][q] + bj;
                    }
                }
            }
        }
    }
}

extern "C" void kernel_launch(void* const* d_in, const int* in_sizes, int n_in,
                              void* d_out, int out_size, void* d_ws, size_t ws_size,
                              hipStream_t stream)
{
    const float* x     = (const float*)d_in[0];
    const float* evals = (const float*)d_in[1];
    const float* evecs = (const float*)d_in[2];
    const float* dtime = (const float*)d_in[3];
    const float* W     = (const float*)d_in[4];
    const float* bias  = (const float*)d_in[5];
    float* out = (float*)d_out;

    const int B = in_sizes[1] / NN;   // evals is (B, 87)

    const size_t w_bytes = (size_t)(2 * PANEL) * sizeof(short);
    if (ws_size >= w_bytes) {
        short* wsb = (short*)d_ws;
        prep_w<<<(2 * PANEL + NT - 1) / NT, NT, 0, stream>>>(W, wsb);
        fused<false><<<dim3(B), dim3(NT), 0, stream>>>(x, evals, evecs, dtime, W, bias, wsb, out);
    } else {
        fused<true><<<dim3(B), dim3(NT), 0, stream>>>(x, evals, evecs, dtime, W, bias, nullptr, out);
    }
}